// Round 13
// baseline (148.176 us; speedup 1.0000x reference)
//
#include <hip/hip_runtime.h>

#define DIMN 32
#define HD   32
#define FN   16
#define FE   8
#define NG   64
#define CAP  64          // bucket capacity (in-degree ~Poisson(16); fallback below)
#define K3T  512
#define K3W  (K3T / 64)  // 8 waves; TWO nodes per wave -> 16 nodes/block
#define K3NPB (K3W * 2)

// K1: out = relu(x @ lin0_w^T + lin0_b); zero deg/aggfb/u; init bucket slot 0
// (so clamped tail reads of empty buckets hit valid memory, not poison).
__global__ __launch_bounds__(256) void k1_out(
    const float* __restrict__ x, const float* __restrict__ lin0_w,
    const float* __restrict__ lin0_b,
    float* __restrict__ outn, float* __restrict__ aggfb, float* __restrict__ u,
    int* __restrict__ deg, int2* __restrict__ es, int N)
{
    const int gt = blockIdx.x * 256 + threadIdx.x;
    if (gt >= N * DIMN) return;
    const int n = gt >> 5, d = gt & 31;

    float s = lin0_b[d];
    const float* xr = x + (size_t)n * FN;
    const float* wr = lin0_w + d * FN;
    #pragma unroll
    for (int j = 0; j < FN; ++j) s = fmaf(xr[j], wr[j], s);
    outn[gt] = fmaxf(s, 0.f);

    aggfb[gt] = 0.f;
    if (d == 0) { deg[n] = 0; es[(size_t)n * CAP] = make_int2(0, 0); }
    if (gt < NG * HD) u[gt] = 0.f;
}

// Kb: bucket edges by destination: es[dst*CAP+pos] = {e, src}.  (R5-proven)
// Overflow (statistically never for Poisson(16) vs CAP=64): compute the message
// directly and atomicAdd into aggfb, which K3 adds before relu.
__global__ __launch_bounds__(256) void kb_bucket(
    const int* __restrict__ ei, const float* __restrict__ ea,
    const float* __restrict__ outn, const float* __restrict__ nn_w,
    const float* __restrict__ nn_b,
    int* __restrict__ deg, int2* __restrict__ es, float* __restrict__ aggfb, int E)
{
    const int e = blockIdx.x * 256 + threadIdx.x;
    if (e >= E) return;
    const int src = ei[e];
    const int dst = ei[E + e];
    const int pos = atomicAdd(&deg[dst], 1);
    if (pos < CAP) {
        es[(size_t)dst * CAP + pos] = make_int2(e, src);
    } else {
        float ef[FE];
        #pragma unroll
        for (int f = 0; f < FE; ++f) ef[f] = ea[(size_t)e * FE + f];
        for (int h = 0; h < HD; ++h) {
            float m = 0.f;
            for (int d = 0; d < DIMN; ++d) {
                float wdh = nn_b[d * HD + h];
                #pragma unroll
                for (int f = 0; f < FE; ++f)
                    wdh = fmaf(ef[f], nn_w[(d * HD + h) * FE + f], wdh);
                m = fmaf(outn[(size_t)src * DIMN + d], wdh, m);
            }
            atomicAdd(aggfb + (size_t)dst * HD + h, m);
        }
    }
}

#define EDGE_FMA_A(o, a) \
    SA += (o); \
    TA0 = fmaf((o), (a).x, TA0);  TA1 = fmaf((o), (a).y, TA1); \
    TA2 = fmaf((o), (a).z, TA2);  TA3 = fmaf((o), (a).w, TA3);
#define EDGE_FMA_B(o, a) \
    SB += (o); \
    TB0 = fmaf((o), (a).x, TB0);  TB1 = fmaf((o), (a).y, TB1); \
    TB2 = fmaf((o), (a).z, TB2);  TB3 = fmaf((o), (a).w, TB3);

// One d-slice of the contraction into accumulator A (uses the wave's s_T/s_SO slot).
#define CONTRIB(DD, A) { \
    const int d_ = d0 + (DD); \
    const float4 ta_ = *(const float4*)&s_T[w * 256 + d_ * 8]; \
    const float4 tb_ = *(const float4*)&s_T[w * 256 + d_ * 8 + 4]; \
    const float2 so_ = s_SO[w * 32 + d_]; \
    const int b_ = d_ * 256 + h; \
    A = fmaf(ta_.x, s_nnw2[b_      ], A); \
    A = fmaf(ta_.y, s_nnw2[b_ +  32], A); \
    A = fmaf(ta_.z, s_nnw2[b_ +  64], A); \
    A = fmaf(ta_.w, s_nnw2[b_ +  96], A); \
    A = fmaf(tb_.x, s_nnw2[b_ + 128], A); \
    A = fmaf(tb_.y, s_nnw2[b_ + 160], A); \
    A = fmaf(tb_.z, s_nnw2[b_ + 192], A); \
    A = fmaf(tb_.w, s_nnw2[b_ + 224], A); \
    A = fmaf(so_.x, s_nnb[d_ * 32 + h], A); \
    A = fmaf(so_.y, s_rw [d_ * 32 + h], A); }

// K3: TWO nodes per wave, edge loops interleaved branchless (chunk-4 per node,
// 16 vector loads in flight from 2 INDEPENDENT chains -> per-wave ILP doubles
// at unchanged occupancy). Weights staged once per block (R12-proven). Tail
// masking is branchless; empty buckets read k1's dummy slot 0 (valid memory).
__global__ __launch_bounds__(K3T, 6) void k3_gather(
    const float* __restrict__ ea, const float* __restrict__ outn,
    const int2* __restrict__ es, const float* __restrict__ nn_w,
    const float* __restrict__ nn_b, const float* __restrict__ root_w,
    const float* __restrict__ conv_b, const int* __restrict__ deg,
    const float* __restrict__ aggfb, const int* __restrict__ batch,
    float* __restrict__ u, int N)
{
    __shared__ float  s_nnw2[DIMN * FE * HD];  // [(d*8+f)*32 + h]  32 KB
    __shared__ float  s_nnb[DIMN * HD];        // 4 KB
    __shared__ float  s_rw[DIMN * HD];         // 4 KB
    __shared__ float  s_cb[HD];
    __shared__ float  s_T[K3W * 256];          // 8 KB (per-wave T slot, reused A->B)
    __shared__ float2 s_SO[K3W * 32];          // 2 KB (reused A->B)
    __shared__ float  s_V[K3NPB * 32];         // 2 KB (per-node result)
    __shared__ int    s_G[K3NPB];

    const int tid = threadIdx.x;
    for (int i = tid; i < DIMN * FE * HD; i += K3T) {
        const int d = i >> 8, rem = i & 255, hh = rem >> 3, f = rem & 7;
        s_nnw2[(d * 8 + f) * 32 + hh] = nn_w[i];   // nn_w[i] = nn_w[(d*32+hh)*8+f]
    }
    for (int i = tid; i < DIMN * HD; i += K3T) { s_nnb[i] = nn_b[i]; s_rw[i] = root_w[i]; }
    if (tid < HD) s_cb[tid] = conv_b[tid];
    __syncthreads();

    const int l = tid & 63;
    const int h = l & 31;
    const int p = l >> 5;
    const int w = tid >> 6;
    const int nA = blockIdx.x * K3NPB + 2 * w;     // wave handles nodes nA, nA+1

    int gA = -1, gB = -1;
    if (nA < N) {
        const int nuA = __builtin_amdgcn_readfirstlane(nA);
        const bool vB = (nuA + 1) < N;
        const int nuB = vB ? nuA + 1 : nuA;          // safe address
        const int dnA = min(deg[nuA], CAP);          // uniform -> s_load
        const int dnB = vB ? min(deg[nuB], CAP) : 0;
        const int2* epA = es + (size_t)nuA * CAP;
        const int2* epB = es + (size_t)nuB * CAP;
        const int jmA = max(dnA - 1, 0);             // slot 0 always valid (k1)
        const int jmB = max(dnB - 1, 0);
        const int dmax = max(dnA, dnB);
        const int f0 = 4 * p;

        float TA0 = 0.f, TA1 = 0.f, TA2 = 0.f, TA3 = 0.f, SA = 0.f;
        float TB0 = 0.f, TB1 = 0.f, TB2 = 0.f, TB3 = 0.f, SB = 0.f;

        for (int j0 = 0; j0 < dmax; j0 += 4) {
            // 8 uniform index loads (SGPR), clamped per node.
            const int2 A0 = epA[min(j0 + 0, jmA)];
            const int2 A1 = epA[min(j0 + 1, jmA)];
            const int2 A2 = epA[min(j0 + 2, jmA)];
            const int2 A3 = epA[min(j0 + 3, jmA)];
            const int2 B0 = epB[min(j0 + 0, jmB)];
            const int2 B1 = epB[min(j0 + 1, jmB)];
            const int2 B2 = epB[min(j0 + 2, jmB)];
            const int2 B3 = epB[min(j0 + 3, jmB)];

            // 16 independent vector loads from TWO independent chains.
            const float4 aA0 = *(const float4*)(ea + (size_t)A0.x * FE + f0);
            const float4 aA1 = *(const float4*)(ea + (size_t)A1.x * FE + f0);
            const float4 aA2 = *(const float4*)(ea + (size_t)A2.x * FE + f0);
            const float4 aA3 = *(const float4*)(ea + (size_t)A3.x * FE + f0);
            const float4 aB0 = *(const float4*)(ea + (size_t)B0.x * FE + f0);
            const float4 aB1 = *(const float4*)(ea + (size_t)B1.x * FE + f0);
            const float4 aB2 = *(const float4*)(ea + (size_t)B2.x * FE + f0);
            const float4 aB3 = *(const float4*)(ea + (size_t)B3.x * FE + f0);
            float oA0 = outn[(size_t)A0.y * DIMN + h];
            float oA1 = outn[(size_t)A1.y * DIMN + h];
            float oA2 = outn[(size_t)A2.y * DIMN + h];
            float oA3 = outn[(size_t)A3.y * DIMN + h];
            float oB0 = outn[(size_t)B0.y * DIMN + h];
            float oB1 = outn[(size_t)B1.y * DIMN + h];
            float oB2 = outn[(size_t)B2.y * DIMN + h];
            float oB3 = outn[(size_t)B3.y * DIMN + h];

            // Branchless masks (uniform conditions -> cndmask).
            oA0 = (j0 + 0 < dnA) ? oA0 : 0.f;
            oA1 = (j0 + 1 < dnA) ? oA1 : 0.f;
            oA2 = (j0 + 2 < dnA) ? oA2 : 0.f;
            oA3 = (j0 + 3 < dnA) ? oA3 : 0.f;
            oB0 = (j0 + 0 < dnB) ? oB0 : 0.f;
            oB1 = (j0 + 1 < dnB) ? oB1 : 0.f;
            oB2 = (j0 + 2 < dnB) ? oB2 : 0.f;
            oB3 = (j0 + 3 < dnB) ? oB3 : 0.f;

            EDGE_FMA_A(oA0, aA0) EDGE_FMA_A(oA1, aA1)
            EDGE_FMA_A(oA2, aA2) EDGE_FMA_A(oA3, aA3)
            EDGE_FMA_B(oB0, aB0) EDGE_FMA_B(oB1, aB1)
            EDGE_FMA_B(oB2, aB2) EDGE_FMA_B(oB3, aB3)
        }

        const int d0 = p << 4;

        // ---- node A epilogue (same-wave DS ops are in-order: safe slot reuse) ----
        *(float4*)&s_T[w * 256 + h * 8 + f0] = make_float4(TA0, TA1, TA2, TA3);
        if (p == 0) s_SO[w * 32 + h] = make_float2(SA, outn[(size_t)nuA * DIMN + h]);
        {
            const float base = aggfb[(size_t)nuA * HD + h] + s_cb[h];
            float acc0 = 0.f, acc1 = 0.f, acc2 = 0.f, acc3 = 0.f;
            #pragma unroll
            for (int dd = 0; dd < 16; dd += 4) {
                CONTRIB(dd + 0, acc0)
                CONTRIB(dd + 1, acc1)
                CONTRIB(dd + 2, acc2)
                CONTRIB(dd + 3, acc3)
            }
            float acc = (acc0 + acc1) + (acc2 + acc3);
            acc += __shfl_xor(acc, 32);
            const float v = fmaxf(acc + base, 0.f);
            if (p == 0) s_V[(2 * w) * 32 + h] = v;
            gA = batch[nuA];
        }

        // ---- node B epilogue ----
        if (vB) {
            *(float4*)&s_T[w * 256 + h * 8 + f0] = make_float4(TB0, TB1, TB2, TB3);
            if (p == 0) s_SO[w * 32 + h] = make_float2(SB, outn[(size_t)nuB * DIMN + h]);
            const float base = aggfb[(size_t)nuB * HD + h] + s_cb[h];
            float acc0 = 0.f, acc1 = 0.f, acc2 = 0.f, acc3 = 0.f;
            #pragma unroll
            for (int dd = 0; dd < 16; dd += 4) {
                CONTRIB(dd + 0, acc0)
                CONTRIB(dd + 1, acc1)
                CONTRIB(dd + 2, acc2)
                CONTRIB(dd + 3, acc3)
            }
            float acc = (acc0 + acc1) + (acc2 + acc3);
            acc += __shfl_xor(acc, 32);
            const float v = fmaxf(acc + base, 0.f);
            if (p == 0) s_V[(2 * w + 1) * 32 + h] = v;
            gB = batch[nuB];
        }
    }
    if (l == 0) { s_G[2 * w] = gA; s_G[2 * w + 1] = gB; }
    __syncthreads();

    // Block-level run-length pool over the 16 consecutive nodes (batch sorted).
    if (tid < 32) {
        float accp = 0.f;
        int   gc   = -1;
        #pragma unroll
        for (int ww = 0; ww < K3NPB; ++ww) {
            const int gg = s_G[ww];
            if (gg >= 0) {
                const float vv = s_V[ww * 32 + tid];
                if (gg != gc) {
                    if (gc >= 0) atomicAdd(u + (size_t)gc * HD + tid, accp);
                    gc = gg;
                    accp = vv;
                } else {
                    accp += vv;
                }
            }
        }
        if (gc >= 0) atomicAdd(u + (size_t)gc * HD + tid, accp);
    }
}

// K4: head — o = relu(u@lin1_w^T + lin1_b); out = o@lin2_w^T + lin2_b.
// Separate dispatch (R6-proven; fusing it regressed in R7).
__global__ __launch_bounds__(64) void k4_head(
    const float* __restrict__ u, const float* __restrict__ lin1_w,
    const float* __restrict__ lin1_b, const float* __restrict__ lin2_w,
    const float* __restrict__ lin2_b, float* __restrict__ outp)
{
    const int g = threadIdx.x;
    if (g >= NG) return;

    float ur[HD];
    #pragma unroll
    for (int hh = 0; hh < HD; ++hh) ur[hh] = u[(size_t)g * HD + hh];

    float acc = lin2_b[0];
    #pragma unroll
    for (int i = 0; i < 16; ++i) {
        float o = lin1_b[i];
        #pragma unroll
        for (int hh = 0; hh < HD; ++hh)
            o = fmaf(ur[hh], lin1_w[i * HD + hh], o);
        o = fmaxf(o, 0.f);
        acc = fmaf(o, lin2_w[i], acc);
    }
    outp[g] = acc;
}

extern "C" void kernel_launch(void* const* d_in, const int* in_sizes, int n_in,
                              void* d_out, int out_size, void* d_ws, size_t ws_size,
                              hipStream_t stream)
{
    const float* x      = (const float*)d_in[0];
    const int*   ei     = (const int*)  d_in[1];
    const float* ea     = (const float*)d_in[2];
    const int*   batch  = (const int*)  d_in[3];
    const float* lin0_w = (const float*)d_in[4];
    const float* lin0_b = (const float*)d_in[5];
    const float* nn_w   = (const float*)d_in[6];
    const float* nn_b   = (const float*)d_in[7];
    const float* root_w = (const float*)d_in[8];
    const float* conv_b = (const float*)d_in[9];
    const float* lin1_w = (const float*)d_in[10];
    const float* lin1_b = (const float*)d_in[11];
    const float* lin2_w = (const float*)d_in[12];
    const float* lin2_b = (const float*)d_in[13];

    const int N = in_sizes[0] / FN;   // 12500
    const int E = in_sizes[2] / FE;   // 200000

    float* ws    = (float*)d_ws;
    float* outn  = ws;                           // N*32
    float* aggfb = outn  + (size_t)N * DIMN;     // N*32 (overflow fallback)
    float* u     = aggfb + (size_t)N * DIMN;     // 64*32
    int*   deg   = (int*)(u + (size_t)NG * HD);  // N
    int2*  es    = (int2*)(deg + N);             // N*CAP int2 (8B-aligned)

    const int nb1 = (N * DIMN + 255) / 256;      // 1563
    k1_out<<<nb1, 256, 0, stream>>>(x, lin0_w, lin0_b, outn, aggfb, u, deg, es, N);

    const int nbb = (E + 255) / 256;             // 782
    kb_bucket<<<nbb, 256, 0, stream>>>(ei, ea, outn, nn_w, nn_b, deg, es, aggfb, E);

    const int nb3 = (N + K3NPB - 1) / K3NPB;     // 782 (16 nodes/block, 2/wave)
    k3_gather<<<nb3, K3T, 0, stream>>>(ea, outn, es, nn_w, nn_b, root_w, conv_b,
                                       deg, aggfb, batch, u, N);

    k4_head<<<1, 64, 0, stream>>>(u, lin1_w, lin1_b, lin2_w, lin2_b, (float*)d_out);
}